// Round 7
// baseline (228.296 us; speedup 1.0000x reference)
//
#include <hip/hip_runtime.h>
#include <stdint.h>
#include <stddef.h>

// Problem constants
#define B_ 4
#define L_ 8192
#define D_ 512
#define M_ (B_*L_)      // 32768 rows
#define K_ 512
#define CHUNK 64
#define NC (L_/CHUNK)   // 128 chunks per sequence

typedef _Float16 f16;
typedef f16 f16x2 __attribute__((ext_vector_type(2)));
typedef f16 f16x4 __attribute__((ext_vector_type(4)));
typedef f16 f16x8 __attribute__((ext_vector_type(8)));
typedef float f32x4 __attribute__((ext_vector_type(4)));

// ---------------- async global->LDS (16B/lane) ----------------
__device__ __forceinline__ void async16(const void* g, void* l) {
  __builtin_amdgcn_global_load_lds(
      (const __attribute__((address_space(1))) uint32_t*)g,
      (__attribute__((address_space(3))) uint32_t*)l,
      16, 0, 0);
}

// ---------------- prep: cvt + pack with baked XOR swizzle -----------------
// Writes xh / wp with 16B units permuted within each 128B row-segment:
//   unit u -> u ^ (row & 7)
// so that gemm's LINEAR global_load_lds lands a swizzled image in LDS and
// swizzled ds_reads are bank-conflict-optimal at 128B row stride (rule 21:
// source permutation == read permutation, LDS dest stays linear).
// Each thread handles one 8-f16 unit (reads 8 floats).
//   x units:  B*L*D/8 = 2,097,152  -> 8192 blocks of 256
//   w units:  2*D*D/8 =    65,536  ->  256 blocks of 256
// (R6 crash root cause: launched 32768 x-blocks for 8-wide threads -> OOB.)
__global__ __launch_bounds__(256) void prep(const float* __restrict__ x,
                                            const float* __restrict__ Wg,
                                            const float* __restrict__ Wc,
                                            f16* __restrict__ xh,
                                            f16* __restrict__ wp) {
  const int bid = blockIdx.x;
  const int isX = (bid < 8192);
  const int U = (isX ? bid : (bid - 8192)) * 256 + threadIdx.x;  // unit idx
  const int r  = U >> 6;               // row (512 f16 = 64 units per row)
  const int w_ = U & 63;               // unit within row
  const int s  = w_ >> 3;              // 128B segment (8 per row)
  const int u3 = w_ & 7;               // unit within segment
  const int du = (r << 6) + (s << 3) + (u3 ^ (r & 7));   // dest unit
  const float* src;
  if (isX)            src = x + (size_t)U * 8;
  else if (r < 512)   src = Wg + (size_t)r * 512 + w_ * 8;
  else                src = Wc + (size_t)(r - 512) * 512 + w_ * 8;
  float4 v0 = *(const float4*)src;
  float4 v1 = *(const float4*)(src + 4);
  f16x8 o = {(f16)v0.x, (f16)v0.y, (f16)v0.z, (f16)v0.w,
             (f16)v1.x, (f16)v1.y, (f16)v1.z, (f16)v1.w};
  f16* dst = isX ? xh : wp;
  *(f16x8*)(dst + (size_t)du * 8) = o;
}

// ---------------- fused dual-B GEMM + activations + chunk composites ------
// v7 = v6 re-test (v6 never ran; crash was prep's grid OOB).
// BK=64: 8 K-steps / 8 barriers instead of 16. Rationale: R4 (schedule) and
// R5 (tile/DMA volume) both null at ~70us; occupancy hard-capped at
// 2 waves/SIMD by the ~244-reg wave (116 VGPR + 128 acc), so the exposed
// per-barrier drain latency is the binding term -> halve barrier count,
// double per-barrier work. LDS 128KB (1 block/CU, unchanged residency).
// Frag ds_reads use the XOR swizzle baked into xh/wp by prep.
__global__ __launch_bounds__(512, 2) void gemm_act(
    const f16* __restrict__ Xh, const f16* __restrict__ Wp,
    const float* __restrict__ bg, const float* __restrict__ bc,
    uint32_t* __restrict__ AC,
    float* __restrict__ cA, float* __restrict__ cB) {
  __shared__ __align__(16) f16 sA[2][256 * 64];    // 2 x 32 KB
  __shared__ __align__(16) f16 sBg[2][128 * 64];   // 2 x 16 KB
  __shared__ __align__(16) f16 sBc[2][128 * 64];   // 2 x 16 KB => 128 KB

  const int tid = threadIdx.x;
  // XCD swizzle: contiguous range per XCD (512 = 8 * 64, bijective)
  const int id = blockIdx.x;           // 0..511
  const int xcd = id & 7;
  const int slot = id >> 3;            // 0..63
  const int g_ = xcd * 64 + slot;
  const int bm = g_ >> 2;              // 0..127 (256-row tiles)
  const int bn = g_ & 3;               // 0..3 (128-col tiles)

  const int lane = tid & 63;
  const int w = tid >> 6;              // 0..7
  const int wm = w >> 1, wn = w & 1;   // 4x2 wave grid over 256x128
  const int l15 = lane & 15, quad = lane >> 4;

  // staging: tid -> (row = tid>>3, 16B unit = tid&7); 64 rows per inst
  const int srow = tid >> 3;           // 0..63
  const int sp8 = (tid & 7) * 8;       // f16 offset of unit (raw linear read)
  const f16* gA  = Xh + (size_t)(bm * 256 + srow) * K_ + sp8;
  const f16* gBg = Wp + (size_t)(bn * 128 + srow) * K_ + sp8;
  const f16* gBc = Wp + (size_t)(512 + bn * 128 + srow) * K_ + sp8;

  // swizzled frag-read unit offsets (f16 elems): k32=0 and k32=1
  // desired original unit (k32*4 + quad) lives at LDS unit
  // (k32*4+quad) ^ (row&7), and row&7 == l15&7 for all frag rows.
  const int xu0 = (quad ^ (l15 & 7)) * 8;
  const int xu1 = xu0 ^ 32;            // == ((4+quad)^(l15&7))*8 since quad<4

  f32x4 accG[4][4] = {};
  f32x4 accC[4][4] = {};

#define STAGE(kk, b) { \
    async16(gA + (kk),                    &sA[b][tid * 8]); \
    async16(gA + (size_t) 64 * K_ + (kk), &sA[b][tid * 8 +  64 * 64]); \
    async16(gA + (size_t)128 * K_ + (kk), &sA[b][tid * 8 + 128 * 64]); \
    async16(gA + (size_t)192 * K_ + (kk), &sA[b][tid * 8 + 192 * 64]); \
    async16(gBg + (kk),                   &sBg[b][tid * 8]); \
    async16(gBg + (size_t)64 * K_ + (kk), &sBg[b][tid * 8 + 64 * 64]); \
    async16(gBc + (kk),                   &sBc[b][tid * 8]); \
    async16(gBc + (size_t)64 * K_ + (kk), &sBc[b][tid * 8 + 64 * 64]); }

#define COMPUTE(bC) { \
    _Pragma("unroll") \
    for (int k32 = 0; k32 < 2; k32++) { \
      const int xu = k32 ? xu1 : xu0; \
      f16x8 af[4], bgf[4], bcf[4]; \
      _Pragma("unroll") \
      for (int i = 0; i < 4; i++) \
        af[i] = *(const f16x8*)(&sA[bC][(wm * 64 + i * 16 + l15) * 64 + xu]); \
      _Pragma("unroll") \
      for (int j = 0; j < 4; j++) { \
        bgf[j] = *(const f16x8*)(&sBg[bC][(wn * 64 + j * 16 + l15) * 64 + xu]); \
        bcf[j] = *(const f16x8*)(&sBc[bC][(wn * 64 + j * 16 + l15) * 64 + xu]); \
      } \
      _Pragma("unroll") \
      for (int i = 0; i < 4; i++) \
        _Pragma("unroll") \
        for (int j = 0; j < 4; j++) { \
          accG[i][j] = __builtin_amdgcn_mfma_f32_16x16x32_f16(af[i], bgf[j], accG[i][j], 0, 0, 0); \
          accC[i][j] = __builtin_amdgcn_mfma_f32_16x16x32_f16(af[i], bcf[j], accC[i][j], 0, 0, 0); \
        } \
    } }

  // Prologue: stage K-tile 0 into buf 0.
  STAGE(0, 0);
  asm volatile("s_waitcnt vmcnt(0)" ::: "memory");
  __builtin_amdgcn_s_barrier();

  // Steady state: stage t+1 into n while computing t from c. 8 K-steps.
#pragma unroll
  for (int t = 0; t < 7; t++) {
    const int c = t & 1, n = c ^ 1;
    STAGE((t + 1) * 64, n);
    COMPUTE(c);
    asm volatile("s_waitcnt vmcnt(0)" ::: "memory");
    __builtin_amdgcn_s_barrier();
  }
  COMPUTE(1);                          // K-step 7
#undef COMPUTE
#undef STAGE

  // Epilogue: sigmoid/tanh, pack (a,b) f16x2 -> AC, and per-chunk (P,Q).
  // Wave wm owns rows [wm*64, wm*64+64) of the 256-row tile = chunk
  // c = bm*4 + wm. Within chunk, t = i*16 + quad*4 + r.
  const int c = bm * 4 + wm;           // global chunk index 0..511
#pragma unroll
  for (int j = 0; j < 4; j++) {
    const int col = bn * 128 + wn * 64 + j * 16 + l15;   // 0..511
    const float bgv = bg[col];
    const float bcv = bc[col];
    float blkP[4], blkQ[4];
#pragma unroll
    for (int i = 0; i < 4; i++) {
      const int mrow = bm * 256 + wm * 64 + i * 16 + quad * 4;
      float P = 1.0f, Q = 0.0f;
#pragma unroll
      for (int r = 0; r < 4; r++) {
        float yg = accG[i][j][r] + bgv;
        float gg = 1.0f / (1.0f + __expf(-yg));        // sigmoid
        float yc = accC[i][j][r] + bcv;
        yc = fminf(fmaxf(yc, -15.0f), 15.0f);
        float t = __expf(2.0f * yc);
        float cc = (t - 1.0f) / (t + 1.0f);            // tanh
        f16x2 p;
        p[0] = (f16)(1.0f - gg);                        // a
        p[1] = (f16)(gg * cc);                          // b
        *(f16x2*)&AC[(size_t)(mrow + r) * 512 + col] = p;
        // compose with the SAME f16-rounded values scan_apply will read
        const float av = (float)p[0];
        const float bv = (float)p[1];
        Q = fmaf(av, Q, bv);                            // seg over r (t asc)
        P *= av;
      }
      // ordered cross-quad compose: quads 0..3 are consecutive t-segments.
      // comp(first,second) = (Ps*Pf, Ps*Qf + Qs)
      float Pp = __shfl_xor(P, 16);
      float Qp = __shfl_xor(Q, 16);
      float nP = P * Pp;
      float nQ = (quad & 1) ? fmaf(P, Qp, Q) : fmaf(Pp, Q, Qp);
      Pp = __shfl_xor(nP, 32);
      Qp = __shfl_xor(nQ, 32);
      blkP[i] = nP * Pp;
      blkQ[i] = (quad & 2) ? fmaf(nP, Qp, nQ) : fmaf(Pp, nQ, Qp);
    }
    // compose the 4 sixteen-row blocks in t order
    float CP = blkP[0], CQ = blkQ[0];
#pragma unroll
    for (int i = 1; i < 4; i++) {
      CQ = fmaf(blkP[i], CQ, blkQ[i]);
      CP *= blkP[i];
    }
    if (quad == 0) {
      cA[(size_t)c * 512 + col] = CP;
      cB[(size_t)c * 512 + col] = CQ;
    }
  }
}

// ---------------- scan: inline chunk-prefix + apply, 16B/lane ---------------
__global__ __launch_bounds__(128) void scan_apply(
    const uint32_t* __restrict__ AC,
    const float* __restrict__ cA, const float* __restrict__ cB,
    float* __restrict__ out) {
  const int blk = blockIdx.x;          // 0..511 = b*NC + ch
  const int ch = blk & (NC - 1);
  const int bseq = blk >> 7;           // NC = 128
  const int d0 = threadIdx.x * 4;      // 128 thr x 4 cols = 512

  float h0 = 0.0f, h1 = 0.0f, h2 = 0.0f, h3 = 0.0f;
  const float* pA = cA + (size_t)(bseq * NC) * 512 + d0;
  const float* pB = cB + (size_t)(bseq * NC) * 512 + d0;
#pragma unroll 4
  for (int cc = 0; cc < ch; cc++) {
    float4 va = *(const float4*)(pA + (size_t)cc * 512);
    float4 vb = *(const float4*)(pB + (size_t)cc * 512);
    h0 = fmaf(va.x, h0, vb.x);
    h1 = fmaf(va.y, h1, vb.y);
    h2 = fmaf(va.z, h2, vb.z);
    h3 = fmaf(va.w, h3, vb.w);
  }

  const size_t base = (size_t)blk * CHUNK * 512 + d0;
#pragma unroll 8
  for (int t = 0; t < CHUNK; t++) {
    const size_t i = base + (size_t)t * 512;
    uint4 v = *(const uint4*)&AC[i];
    f16x2 p0 = __builtin_bit_cast(f16x2, v.x);
    f16x2 p1 = __builtin_bit_cast(f16x2, v.y);
    f16x2 p2 = __builtin_bit_cast(f16x2, v.z);
    f16x2 p3 = __builtin_bit_cast(f16x2, v.w);
    h0 = fmaf((float)p0[0], h0, (float)p0[1]);
    h1 = fmaf((float)p1[0], h1, (float)p1[1]);
    h2 = fmaf((float)p2[0], h2, (float)p2[1]);
    h3 = fmaf((float)p3[0], h3, (float)p3[1]);
    float4 o;
    o.x = h0; o.y = h1; o.z = h2; o.w = h3;
    *(float4*)&out[i] = o;
  }
}

// ---------------- launch ----------------
extern "C" void kernel_launch(void* const* d_in, const int* in_sizes, int n_in,
                              void* d_out, int out_size, void* d_ws, size_t ws_size,
                              hipStream_t stream) {
  const float* x  = (const float*)d_in[0];
  const float* Wg = (const float*)d_in[1];
  const float* bg = (const float*)d_in[2];
  const float* Wc = (const float*)d_in[3];
  const float* bc = (const float*)d_in[4];
  float* out = (float*)d_out;

  char* ws = (char*)d_ws;
  // workspace layout (bytes):
  //   [0, 32MB)      xh   f16 x (swizzled units)
  //   [32MB, 33MB)   wp   f16 packed weights [1024][512] (swizzled units)
  //   [33MB, 97MB)   AC   u32 packed (a,b) f16x2 [32768][512]
  //   [97MB..99MB)   cA, cB fp32 (1MB each)
  f16*      xh = (f16*)(ws);
  f16*      wp = (f16*)(ws + 33554432);
  uint32_t* AC = (uint32_t*)(ws + 34603008);
  float*    cA = (float*)(ws + 101711872);
  float*    cB = (float*)(ws + 102760448);

  prep<<<8448, 256, 0, stream>>>(x, Wg, Wc, xh, wp);                 // cvt + pack (swz)
  gemm_act<<<512, 512, 0, stream>>>(xh, wp, bg, bc, AC, cA, cB);     // 256x128, BK=64
  scan_apply<<<B_ * NC, 128, 0, stream>>>(AC, cA, cB, out);          // 512 blocks
}